// Round 1
// baseline (158.825 us; speedup 1.0000x reference)
//
#include <hip/hip_runtime.h>
#include <math.h>

// ParametricEQ: 5-section cascaded biquad IIR over (32, 131072) signals.
// Exact chunked linear-recurrence decomposition per section:
//   pass (zero-state per chunk) -> scan (chunk-boundary states) -> correct (+ next section, fused)

#define NB 32
#define LCH 32            // chunk length (samples)

__constant__ double c_lo[15] = {-12.0,   20.0, 0.1,
                                -12.0,   20.0, 0.1,
                                -12.0,  200.0, 0.1,
                                -12.0, 2000.0, 0.1,
                                -12.0, 4000.0, 0.1};
__constant__ double c_hi[15] = { 12.0,  2000.0, 10.0,
                                 12.0,   200.0, 10.0,
                                 12.0,  2000.0, 10.0,
                                 12.0, 12000.0, 10.0,
                                 12.0, 16000.0, 10.0};

// ---- coefficients: 32 batches x 5 sections, RBJ cookbook, fp64 internal ----
__global__ void eq_coeffs(const float* __restrict__ cp, float* __restrict__ sos)
{
    int tid = blockIdx.x * blockDim.x + threadIdx.x;
    if (tid >= NB * 5) return;
    int b = tid / 5, k = tid - b * 5;

    double p[3];
#pragma unroll
    for (int j = 0; j < 3; ++j) {
        int i = k * 3 + j;
        double pv = (double)cp[b * 15 + i];
        p[j] = c_lo[i] + pv * (c_hi[i] - c_lo[i]);
    }
    double A     = exp(p[0] * (M_LN10 / 40.0));   // 10^(g/40)
    double w0    = 2.0 * M_PI * p[1] / 44100.0;
    double alpha = sin(w0) / (2.0 * p[2]);
    double cw    = cos(w0);
    double sA    = sqrt(A);

    double b0, b1, b2, a0, a1, a2;
    if (k == 0) {            // low shelf
        b0 =     A * ((A + 1) - (A - 1) * cw + 2 * sA * alpha);
        b1 = 2 * A * ((A - 1) - (A + 1) * cw);
        b2 =     A * ((A + 1) - (A - 1) * cw - 2 * sA * alpha);
        a0 =          (A + 1) + (A - 1) * cw + 2 * sA * alpha;
        a1 =    -2 * ((A - 1) + (A + 1) * cw);
        a2 =          (A + 1) + (A - 1) * cw - 2 * sA * alpha;
    } else if (k == 4) {     // high shelf
        b0 =     A * ((A + 1) + (A - 1) * cw + 2 * sA * alpha);
        b1 = -2 * A * ((A - 1) + (A + 1) * cw);
        b2 =     A * ((A + 1) + (A - 1) * cw - 2 * sA * alpha);
        a0 =          (A + 1) - (A - 1) * cw + 2 * sA * alpha;
        a1 =     2 * ((A - 1) - (A + 1) * cw);
        a2 =          (A + 1) - (A - 1) * cw - 2 * sA * alpha;
    } else {                 // peaking
        b0 = 1.0 + alpha * A;
        b1 = -2.0 * cw;
        b2 = 1.0 - alpha * A;
        a0 = 1.0 + alpha / A;
        a1 = -2.0 * cw;
        a2 = 1.0 - alpha / A;
    }
    double inv = 1.0 / a0;
    float* o = sos + (size_t)(b * 5 + k) * 6;
    o[0] = (float)(b0 * inv);
    o[1] = (float)(b1 * inv);
    o[2] = (float)(b2 * inv);
    o[3] = 1.0f;
    o[4] = (float)(a1 * inv);
    o[5] = (float)(a2 * inv);
}

// ---- pass kernel: optionally correct section kc's zero-state output with its
// incoming chunk state (homogeneous response), optionally apply section ka's
// zero-state biquad; one thread = one chunk of LCH samples. ----
template<bool CORR, bool APPLY>
__global__ __launch_bounds__(256)
void eq_pass(const float* __restrict__ in, float* __restrict__ out,
             const float* __restrict__ sos,
             const float2* __restrict__ zin, float2* __restrict__ vout,
             int kc, int ka, int C, int T)
{
    int tid = blockIdx.x * blockDim.x + threadIdx.x;
    int b = tid / C;
    int c = tid - b * C;
    if (b >= NB) return;

    const float* xp = in  + (size_t)b * T + (size_t)c * LCH;
    float*       yp = out + (size_t)b * T + (size_t)c * LCH;

    float ca1 = 0.f, ca2 = 0.f, h1 = 0.f, h2 = 0.f;
    if (CORR) {
        const float* s = sos + (size_t)(b * 5 + kc) * 6;
        ca1 = s[4]; ca2 = s[5];
        float2 z = zin[(size_t)b * C + c];
        h1 = z.x; h2 = z.y;
    }
    float b0 = 0.f, b1 = 0.f, b2 = 0.f, a1 = 0.f, a2 = 0.f, z1 = 0.f, z2 = 0.f;
    if (APPLY) {
        const float* s = sos + (size_t)(b * 5 + ka) * 6;
        b0 = s[0]; b1 = s[1]; b2 = s[2]; a1 = s[4]; a2 = s[5];
    }

#pragma unroll
    for (int t0 = 0; t0 < LCH; t0 += 4) {
        float4 xv = *reinterpret_cast<const float4*>(xp + t0);
        float sv[4] = {xv.x, xv.y, xv.z, xv.w};
        float yv[4];
#pragma unroll
        for (int j = 0; j < 4; ++j) {
            float s = sv[j];
            if (CORR) {
                s += h1;                          // y_h contribution = z1h
                float n1 = fmaf(-ca1, h1, h2);    // z1h' = -a1*z1h + z2h
                float n2 = -ca2 * h1;             // z2h' = -a2*z1h
                h1 = n1; h2 = n2;
            }
            float y;
            if (APPLY) {
                y        = fmaf(b0, s, z1);       // y = b0*s + z1
                float u  = fmaf(b1, s, z2);       // b1*s + z2
                z1       = fmaf(-a1, y, u);       // z1' = b1*s - a1*y + z2
                z2       = fmaf(-a2, y, b2 * s);  // z2' = b2*s - a2*y
            } else {
                y = s;
            }
            yv[j] = y;
        }
        *reinterpret_cast<float4*>(yp + t0) = make_float4(yv[0], yv[1], yv[2], yv[3]);
    }
    if (APPLY) vout[(size_t)b * C + c] = make_float2(z1, z2);
}

// ---- scan kernel: per batch (one 64-lane wave), compute incoming state for
// every chunk:  S_0 = 0,  S_{c+1} = M^LCH * S_c + v_c.  Constant-matrix affine
// scan: per-lane serial over C/64 chunks + Kogge-Stone over lanes. fp64. ----
__global__ __launch_bounds__(64)
void eq_scan(const float2* __restrict__ v, float2* __restrict__ zin,
             const float* __restrict__ sos, int k, int C)
{
    int b = blockIdx.x;
    int l = threadIdx.x;   // 0..63
    const float* sp = sos + (size_t)(b * 5 + k) * 6;
    double a1 = (double)sp[4], a2 = (double)sp[5];

    // M = [[-a1, 1], [-a2, 0]]
    double m00 = -a1, m01 = 1.0, m10 = -a2, m11 = 0.0;
    // M_L = M^LCH (LCH=32 -> 5 squarings)
#pragma unroll
    for (int i = 0; i < 5; ++i) {
        double n00 = m00 * m00 + m01 * m10, n01 = m00 * m01 + m01 * m11;
        double n10 = m10 * m00 + m11 * m10, n11 = m10 * m01 + m11 * m11;
        m00 = n00; m01 = n01; m10 = n10; m11 = n11;
    }
    double L00 = m00, L01 = m01, L10 = m10, L11 = m11;
    // M_K = M_L^(KL) with KL = C/64 (=64 -> 6 squarings)
#pragma unroll
    for (int i = 0; i < 6; ++i) {
        double n00 = m00 * m00 + m01 * m10, n01 = m00 * m01 + m01 * m11;
        double n10 = m10 * m00 + m11 * m10, n11 = m10 * m01 + m11 * m11;
        m00 = n00; m01 = n01; m10 = n10; m11 = n11;
    }
    double K00 = m00, K01 = m01, K10 = m10, K11 = m11;

    int KL = C / 64;
    size_t base = (size_t)b * C + (size_t)l * KL;

    // local segment contribution (from zero entry state)
    double s1 = 0.0, s2 = 0.0;
    for (int j = 0; j < KL; ++j) {
        float2 vv = v[base + j];
        double n1 = L00 * s1 + L01 * s2 + (double)vv.x;
        double n2 = L10 * s1 + L11 * s2 + (double)vv.y;
        s1 = n1; s2 = n2;
    }

    // Kogge-Stone inclusive scan across lanes; multiplier for distance d is
    // M_K^d, maintained by squaring between steps.
    double k00 = K00, k01 = K01, k10 = K10, k11 = K11;
    for (int d = 1; d < 64; d <<= 1) {
        double u1 = __shfl_up(s1, d);
        double u2 = __shfl_up(s2, d);
        if (l >= d) {
            double n1 = k00 * u1 + k01 * u2 + s1;
            double n2 = k10 * u1 + k11 * u2 + s2;
            s1 = n1; s2 = n2;
        }
        double n00 = k00 * k00 + k01 * k10, n01 = k00 * k01 + k01 * k11;
        double n10 = k10 * k00 + k11 * k10, n11 = k10 * k01 + k11 * k11;
        k00 = n00; k01 = n01; k10 = n10; k11 = n11;
    }

    // exclusive prefix = inclusive shifted by one lane
    double e1 = __shfl_up(s1, 1);
    double e2 = __shfl_up(s2, 1);
    if (l == 0) { e1 = 0.0; e2 = 0.0; }

    // replay local chunks, emitting incoming state per chunk
    s1 = e1; s2 = e2;
    for (int j = 0; j < KL; ++j) {
        zin[base + j] = make_float2((float)s1, (float)s2);
        float2 vv = v[base + j];
        double n1 = L00 * s1 + L01 * s2 + (double)vv.x;
        double n2 = L10 * s1 + L11 * s2 + (double)vv.y;
        s1 = n1; s2 = n2;
    }
}

extern "C" void kernel_launch(void* const* d_in, const int* in_sizes, int n_in,
                              void* d_out, int out_size, void* d_ws, size_t ws_size,
                              hipStream_t stream)
{
    const int B = NB;
    const int T = in_sizes[0] / B;       // 131072
    const int C = T / LCH;               // 4096 chunks per batch

    const float* x  = (const float*)d_in[0];
    const float* cp = (const float*)d_in[1];
    float* out = (float*)d_out;
    float* sos = out + (size_t)B * T;    // sos tail of d_out: 32*5*6 floats

    float2* vbuf = (float2*)d_ws;                    // [B][C] chunk final states
    float2* zbuf = vbuf + (size_t)B * C;             // [B][C] chunk incoming states

    eq_coeffs<<<dim3(1), dim3(256), 0, stream>>>(cp, sos);

    int nthr = B * C;
    dim3 grd(nthr / 256), blk(256);

    // section 0: zero-state pass (reads x, writes y_zs into d_out y region)
    eq_pass<false, true><<<grd, blk, 0, stream>>>(x, out, sos, nullptr, vbuf, -1, 0, C, T);

    for (int k = 1; k < 5; ++k) {
        eq_scan<<<dim3(B), dim3(64), 0, stream>>>(vbuf, zbuf, sos, k - 1, C);
        // correct section k-1, apply section k (in-place on d_out y region)
        eq_pass<true, true><<<grd, blk, 0, stream>>>(out, out, sos, zbuf, vbuf, k - 1, k, C, T);
    }

    eq_scan<<<dim3(B), dim3(64), 0, stream>>>(vbuf, zbuf, sos, 4, C);
    // final correction of section 4 (in-place)
    eq_pass<true, false><<<grd, blk, 0, stream>>>(out, out, sos, zbuf, nullptr, 4, -1, C, T);
}

// Round 2
// 50.991 us; speedup vs baseline: 3.1147x; 3.1147x over previous
//
#include <hip/hip_runtime.h>
#include <math.h>

// ParametricEQ: 5-section cascaded biquad over (32, 131072).
// Single 10-state linear-recurrence decomposition:
//   K1 setup: coeffs + A = one-sample cascade matrix + powers P_m = A^(32*2^m)
//   K2 pass1: per-chunk zero-state cascade -> v states + per-span totals (in-wave KS)
//   K3: per-batch KS over 64 span totals -> span seeds
//   K4 pass2: seed-shifted in-wave KS -> exact chunk entry states -> cascade -> y

#define NB 32
#define LCH 32
#define T_LEN 131072
#define C_CH (T_LEN / LCH)     // 4096 chunks per batch
#define SPANS (C_CH / 64)      // 64 spans per batch (64 chunks each)
#define NPOW 12                // P_m = A^(32*2^m), m = 0..11

__constant__ double c_lo[15] = {-12.0,   20.0, 0.1,
                                -12.0,   20.0, 0.1,
                                -12.0,  200.0, 0.1,
                                -12.0, 2000.0, 0.1,
                                -12.0, 4000.0, 0.1};
__constant__ double c_hi[15] = { 12.0,  2000.0, 10.0,
                                 12.0,   200.0, 10.0,
                                 12.0,  2000.0, 10.0,
                                 12.0, 12000.0, 10.0,
                                 12.0, 16000.0, 10.0};

// ---------------- K1: coeffs + cascade matrix powers (per-batch block) -------
__global__ __launch_bounds__(128)
void eq_setup(const float* __restrict__ cp, float* __restrict__ sos_out,
              float* __restrict__ powers)
{
    int b = blockIdx.x;
    int t = threadIdx.x;
    __shared__ float  sc[5][5];            // b0,b1,b2,a1,a2 per section (fp32-rounded)
    __shared__ double Abuf[2][10][10];

    if (t < 5) {
        int k = t;
        double p[3];
#pragma unroll
        for (int j = 0; j < 3; ++j) {
            int i = k * 3 + j;
            double pv = (double)cp[b * 15 + i];
            p[j] = c_lo[i] + pv * (c_hi[i] - c_lo[i]);
        }
        double A     = exp(p[0] * (M_LN10 / 40.0));
        double w0    = 2.0 * M_PI * p[1] / 44100.0;
        double alpha = sin(w0) / (2.0 * p[2]);
        double cw    = cos(w0);
        double sA    = sqrt(A);
        double b0, b1, b2, a0, a1, a2;
        if (k == 0) {            // low shelf
            b0 =     A * ((A + 1) - (A - 1) * cw + 2 * sA * alpha);
            b1 = 2 * A * ((A - 1) - (A + 1) * cw);
            b2 =     A * ((A + 1) - (A - 1) * cw - 2 * sA * alpha);
            a0 =          (A + 1) + (A - 1) * cw + 2 * sA * alpha;
            a1 =    -2 * ((A - 1) + (A + 1) * cw);
            a2 =          (A + 1) + (A - 1) * cw - 2 * sA * alpha;
        } else if (k == 4) {     // high shelf
            b0 =     A * ((A + 1) + (A - 1) * cw + 2 * sA * alpha);
            b1 = -2 * A * ((A - 1) + (A + 1) * cw);
            b2 =     A * ((A + 1) + (A - 1) * cw - 2 * sA * alpha);
            a0 =          (A + 1) - (A - 1) * cw + 2 * sA * alpha;
            a1 =     2 * ((A - 1) - (A + 1) * cw);
            a2 =          (A + 1) - (A - 1) * cw - 2 * sA * alpha;
        } else {                 // peaking
            b0 = 1.0 + alpha * A;
            b1 = -2.0 * cw;
            b2 = 1.0 - alpha * A;
            a0 = 1.0 + alpha / A;
            a1 = -2.0 * cw;
            a2 = 1.0 - alpha / A;
        }
        double inv = 1.0 / a0;
        float fb0 = (float)(b0 * inv), fb1 = (float)(b1 * inv), fb2 = (float)(b2 * inv);
        float fa1 = (float)(a1 * inv), fa2 = (float)(a2 * inv);
        float* o = sos_out + (size_t)(b * 5 + k) * 6;
        o[0] = fb0; o[1] = fb1; o[2] = fb2; o[3] = 1.0f; o[4] = fa1; o[5] = fa2;
        sc[k][0] = fb0; sc[k][1] = fb1; sc[k][2] = fb2; sc[k][3] = fa1; sc[k][4] = fa2;
    }
    __syncthreads();

    // Build A (10x10): column i = one-sample cascade state-update of basis e_i, x=0.
    // State order: z[2k] = z1_k, z[2k+1] = z2_k.
    if (t < 10) {
        double z[10];
#pragma unroll
        for (int i = 0; i < 10; ++i) z[i] = 0.0;
        z[t] = 1.0;
        double s = 0.0;
        double zn[10];
#pragma unroll
        for (int k = 0; k < 5; ++k) {
            double b0 = sc[k][0], b1 = sc[k][1], b2 = sc[k][2];
            double a1 = sc[k][3], a2 = sc[k][4];
            double y = b0 * s + z[2 * k];
            zn[2 * k]     = b1 * s - a1 * y + z[2 * k + 1];
            zn[2 * k + 1] = b2 * s - a2 * y;
            s = y;
        }
#pragma unroll
        for (int r = 0; r < 10; ++r) Abuf[0][r][t] = zn[r];
    }
    __syncthreads();

    // 16 squarings: after sq, matrix = A^(2^(sq+1)); emit P_m = A^(2^(5+m)).
    int r = t / 10, cc = t % 10;
    int cur = 0;
    for (int sq = 0; sq < 16; ++sq) {
        double acc = 0.0;
        if (t < 100) {
#pragma unroll
            for (int j = 0; j < 10; ++j) acc += Abuf[cur][r][j] * Abuf[cur][j][cc];
        }
        __syncthreads();
        if (t < 100) Abuf[cur ^ 1][r][cc] = acc;
        __syncthreads();
        cur ^= 1;
        if (sq >= 4 && t < 100) {
            int m = sq - 4;   // sq=4 -> A^32 -> P_0
            powers[((size_t)b * NPOW + m) * 100 + t] = (float)Abuf[cur][r][cc];
        }
    }
}

// ---- shared device helpers ----
__device__ __forceinline__ void ks_scan(float sv[10], const float* __restrict__ Pb, int lane)
{
#pragma unroll
    for (int j = 0; j < 6; ++j) {
        const float* P = Pb + j * 100;
        float u[10];
#pragma unroll
        for (int i = 0; i < 10; ++i) u[i] = __shfl_up(sv[i], 1 << j);
        if (lane >= (1 << j)) {
            float ns[10];
#pragma unroll
            for (int rr = 0; rr < 10; ++rr) {
                float acc = sv[rr];
#pragma unroll
                for (int c2 = 0; c2 < 10; ++c2) acc = fmaf(P[rr * 10 + c2], u[c2], acc);
                ns[rr] = acc;
            }
#pragma unroll
            for (int i = 0; i < 10; ++i) sv[i] = ns[i];
        }
    }
}

// ---------------- K2: zero-state chunk pass + span totals ----------------
__global__ __launch_bounds__(64)
void eq_pass1(const float* __restrict__ x, const float* __restrict__ sos,
              const float* __restrict__ powers,
              float* __restrict__ v, float* __restrict__ Tspan)
{
    int blk = blockIdx.x;
    int b = blk / SPANS, sp = blk % SPANS;
    int l = threadIdx.x;
    int c = sp * 64 + l;

    const float* s5 = sos + (size_t)(b * 5) * 6;
    float cb0[5], cb1[5], cb2[5], ca1[5], ca2[5];
#pragma unroll
    for (int k = 0; k < 5; ++k) {
        cb0[k] = s5[k * 6 + 0]; cb1[k] = s5[k * 6 + 1]; cb2[k] = s5[k * 6 + 2];
        ca1[k] = s5[k * 6 + 4]; ca2[k] = s5[k * 6 + 5];
    }
    float z1[5] = {0, 0, 0, 0, 0}, z2[5] = {0, 0, 0, 0, 0};

    const float* xp = x + (size_t)b * T_LEN + (size_t)c * LCH;
#pragma unroll
    for (int t0 = 0; t0 < LCH; t0 += 4) {
        float4 xv = *reinterpret_cast<const float4*>(xp + t0);
        float in4[4] = {xv.x, xv.y, xv.z, xv.w};
#pragma unroll
        for (int j = 0; j < 4; ++j) {
            float s = in4[j];
#pragma unroll
            for (int k = 0; k < 5; ++k) {
                float yk = fmaf(cb0[k], s, z1[k]);
                float u  = fmaf(cb1[k], s, z2[k]);
                z1[k] = fmaf(-ca1[k], yk, u);
                z2[k] = fmaf(-ca2[k], yk, cb2[k] * s);
                s = yk;
            }
        }
    }

    float sv[10];
#pragma unroll
    for (int k = 0; k < 5; ++k) { sv[2 * k] = z1[k]; sv[2 * k + 1] = z2[k]; }

    // store v: layout ((b*SPANS+sp)*10 + i)*64 + l  (lane-fastest, coalesced)
    size_t vb = ((size_t)(b * SPANS + sp) * 10) * 64 + l;
#pragma unroll
    for (int i = 0; i < 10; ++i) v[vb + (size_t)i * 64] = sv[i];

    const float* Pb = powers + (size_t)b * NPOW * 100;
    ks_scan(sv, Pb, l);

    if (l == 63) {
#pragma unroll
        for (int i = 0; i < 10; ++i) Tspan[(size_t)(b * 10 + i) * 64 + sp] = sv[i];
    }
}

// ---------------- K3: per-batch scan over 64 span totals -> seeds ----------
__global__ __launch_bounds__(64)
void eq_seedscan(const float* __restrict__ powers, const float* __restrict__ Tspan,
                 float* __restrict__ seeds)
{
    int b = blockIdx.x;
    int l = threadIdx.x;     // span index
    float sv[10];
#pragma unroll
    for (int i = 0; i < 10; ++i) sv[i] = Tspan[(size_t)(b * 10 + i) * 64 + l];

    const float* Pb = powers + (size_t)b * NPOW * 100 + 6 * 100;  // P_6..P_11
    ks_scan(sv, Pb, l);

    float e[10];
#pragma unroll
    for (int i = 0; i < 10; ++i) e[i] = __shfl_up(sv[i], 1);
    if (l == 0) {
#pragma unroll
        for (int i = 0; i < 10; ++i) e[i] = 0.0f;
    }
#pragma unroll
    for (int i = 0; i < 10; ++i) seeds[(size_t)(b * 10 + i) * 64 + l] = e[i];
}

// ---------------- K4: seeded scan -> exact chunk states -> cascade -> y ----
__global__ __launch_bounds__(64)
void eq_pass2(const float* __restrict__ x, const float* __restrict__ sos,
              const float* __restrict__ powers, const float* __restrict__ v,
              const float* __restrict__ seeds, float* __restrict__ y)
{
    int blk = blockIdx.x;
    int b = blk / SPANS, sp = blk % SPANS;
    int l = threadIdx.x;
    int c = sp * 64 + l;

    // d_l: lane 0 = span seed (entering chunk c0); lane l>=1 = v[c-1]
    float sv[10];
    if (l == 0) {
#pragma unroll
        for (int i = 0; i < 10; ++i) sv[i] = seeds[(size_t)(b * 10 + i) * 64 + sp];
    } else {
        size_t vb = ((size_t)(b * SPANS + sp) * 10) * 64 + (l - 1);
#pragma unroll
        for (int i = 0; i < 10; ++i) sv[i] = v[vb + (size_t)i * 64];
    }

    const float* Pb = powers + (size_t)b * NPOW * 100;
    ks_scan(sv, Pb, l);   // sv = exact entering state of chunk c

    const float* s5 = sos + (size_t)(b * 5) * 6;
    float cb0[5], cb1[5], cb2[5], ca1[5], ca2[5];
#pragma unroll
    for (int k = 0; k < 5; ++k) {
        cb0[k] = s5[k * 6 + 0]; cb1[k] = s5[k * 6 + 1]; cb2[k] = s5[k * 6 + 2];
        ca1[k] = s5[k * 6 + 4]; ca2[k] = s5[k * 6 + 5];
    }
    float z1[5], z2[5];
#pragma unroll
    for (int k = 0; k < 5; ++k) { z1[k] = sv[2 * k]; z2[k] = sv[2 * k + 1]; }

    const float* xp = x + (size_t)b * T_LEN + (size_t)c * LCH;
    float*       yp = y + (size_t)b * T_LEN + (size_t)c * LCH;
#pragma unroll
    for (int t0 = 0; t0 < LCH; t0 += 4) {
        float4 xv = *reinterpret_cast<const float4*>(xp + t0);
        float in4[4] = {xv.x, xv.y, xv.z, xv.w};
        float o4[4];
#pragma unroll
        for (int j = 0; j < 4; ++j) {
            float s = in4[j];
#pragma unroll
            for (int k = 0; k < 5; ++k) {
                float yk = fmaf(cb0[k], s, z1[k]);
                float u  = fmaf(cb1[k], s, z2[k]);
                z1[k] = fmaf(-ca1[k], yk, u);
                z2[k] = fmaf(-ca2[k], yk, cb2[k] * s);
                s = yk;
            }
            o4[j] = s;
        }
        *reinterpret_cast<float4*>(yp + t0) = make_float4(o4[0], o4[1], o4[2], o4[3]);
    }
}

extern "C" void kernel_launch(void* const* d_in, const int* in_sizes, int n_in,
                              void* d_out, int out_size, void* d_ws, size_t ws_size,
                              hipStream_t stream)
{
    const float* x  = (const float*)d_in[0];
    const float* cp = (const float*)d_in[1];
    float* out = (float*)d_out;
    float* sos = out + (size_t)NB * T_LEN;   // sos tail of d_out (32*5*6 floats)

    float* v      = (float*)d_ws;                          // NB*C_CH*10 floats
    float* Tspan  = v + (size_t)NB * C_CH * 10;            // NB*10*64
    float* seeds  = Tspan + (size_t)NB * 10 * 64;          // NB*10*64
    float* powers = seeds + (size_t)NB * 10 * 64;          // NB*NPOW*100

    eq_setup<<<dim3(NB), dim3(128), 0, stream>>>(cp, sos, powers);
    eq_pass1<<<dim3(NB * SPANS), dim3(64), 0, stream>>>(x, sos, powers, v, Tspan);
    eq_seedscan<<<dim3(NB), dim3(64), 0, stream>>>(powers, Tspan, seeds);
    eq_pass2<<<dim3(NB * SPANS), dim3(64), 0, stream>>>(x, sos, powers, v, seeds, out);
}